// Round 9
// baseline (1911.946 us; speedup 1.0000x reference)
//
#include <hip/hip_runtime.h>
#include <cstddef>

static constexpr float ALPHA = 0.2f;
static constexpr int H = 64;
static constexpr int NBMAX = 4096;   // combined buckets (64 nodes each)
static constexpr int BTILE = 2048;   // bfill edges per block (8/thread)

typedef __attribute__((ext_vector_type(8))) short short8;
typedef __attribute__((ext_vector_type(4))) float floatx4;

__device__ __forceinline__ float lrelu(float v) { return v >= 0.0f ? v : ALPHA * v; }

__device__ __forceinline__ float asf(unsigned int u)
{
    union { unsigned int i; float f; } x;
    x.i = u;
    return x.f;
}

__device__ __forceinline__ unsigned short f2b(float f)
{
    union { float f; unsigned int i; } x;
    x.f = f;
    unsigned int r = x.i + 0x7fffu + ((x.i >> 16) & 1u);  // RNE
    return (unsigned short)(r >> 16);
}

// ---- MFMA GEMM: out[rows,64](bf16) = act(in[rows,K] @ W[K,64] (+bias)) (* scl[row]) ----
template <int K, bool AF32, bool BIAS, bool ACT, bool SCALE>
__global__ __launch_bounds__(256) void mfma_gemm(
    const void* __restrict__ in_v, const float* __restrict__ W,
    const float* __restrict__ bias, const float* __restrict__ scl,
    unsigned short* __restrict__ out, int rows)
{
    constexpr int S = K / 32;
    __shared__ short8 WL[4 * S * 64];

    for (int f = threadIdx.x; f < 4 * S * 64; f += 256) {
        int c = f / (S * 64);
        int rem = f % (S * 64);
        int s = rem / 64;
        int l = rem % 64;
        short8 frag;
        #pragma unroll
        for (int j = 0; j < 8; ++j) {
            int k = s * 32 + (l >> 4) * 8 + j;
            int col = c * 16 + (l & 15);
            frag[j] = (short)f2b(W[k * H + col]);
        }
        WL[f] = frag;
    }
    __syncthreads();

    const int l = threadIdx.x & 63;
    const int wv = threadIdx.x >> 6;
    const int rowBase = blockIdx.x * 64 + wv * 16;
    if (rowBase >= rows) return;
    const int arow = min(rowBase + (l & 15), rows - 1);

    floatx4 acc0 = {0.f, 0.f, 0.f, 0.f};
    floatx4 acc1 = {0.f, 0.f, 0.f, 0.f};
    floatx4 acc2 = {0.f, 0.f, 0.f, 0.f};
    floatx4 acc3 = {0.f, 0.f, 0.f, 0.f};

    #pragma unroll
    for (int s = 0; s < S; ++s) {
        short8 a;
        if (AF32) {
            const float* ap = (const float*)in_v + (size_t)arow * K + s * 32 + (l >> 4) * 8;
            float4 f0 = *(const float4*)(ap + 0);
            float4 f1 = *(const float4*)(ap + 4);
            a[0] = (short)f2b(f0.x); a[1] = (short)f2b(f0.y);
            a[2] = (short)f2b(f0.z); a[3] = (short)f2b(f0.w);
            a[4] = (short)f2b(f1.x); a[5] = (short)f2b(f1.y);
            a[6] = (short)f2b(f1.z); a[7] = (short)f2b(f1.w);
        } else {
            a = *(const short8*)((const unsigned short*)in_v + (size_t)arow * K + s * 32 + (l >> 4) * 8);
        }
        acc0 = __builtin_amdgcn_mfma_f32_16x16x32_bf16(a, WL[(0 * S + s) * 64 + l], acc0, 0, 0, 0);
        acc1 = __builtin_amdgcn_mfma_f32_16x16x32_bf16(a, WL[(1 * S + s) * 64 + l], acc1, 0, 0, 0);
        acc2 = __builtin_amdgcn_mfma_f32_16x16x32_bf16(a, WL[(2 * S + s) * 64 + l], acc2, 0, 0, 0);
        acc3 = __builtin_amdgcn_mfma_f32_16x16x32_bf16(a, WL[(3 * S + s) * 64 + l], acc3, 0, 0, 0);
    }

    #pragma unroll
    for (int j = 0; j < 4; ++j) {
        int row = rowBase + (l >> 4) * 4 + j;
        if (row >= rows) continue;
        unsigned short* orow = out + (size_t)row * H;
        float sc = SCALE ? scl[row] : 1.0f;
        float v;
        int col = l & 15;
        v = acc0[j] + (BIAS ? bias[col] : 0.f);      if (ACT) v = lrelu(v); orow[col]      = f2b(v * sc);
        v = acc1[j] + (BIAS ? bias[col + 16] : 0.f); if (ACT) v = lrelu(v); orow[col + 16] = f2b(v * sc);
        v = acc2[j] + (BIAS ? bias[col + 32] : 0.f); if (ACT) v = lrelu(v); orow[col + 32] = f2b(v * sc);
        v = acc3[j] + (BIAS ? bias[col + 48] : 0.f); if (ACT) v = lrelu(v); orow[col + 48] = f2b(v * sc);
    }
}

// ---------------- combined bucket-sort CSR build (64-node buckets, data + meta) ----------------
// virtual buckets: [0, nbD) data (dst>>6), [nbD, nbD+nbM) meta.
// packed entry = (dstLocal<<17) | src   (src < 2^17, dstLocal < 64)

__global__ __launch_bounds__(256) void zero_i(int* __restrict__ p, int n)
{
    int i = blockIdx.x * 256 + threadIdx.x;
    if (i < n) p[i] = 0;
}

__global__ __launch_bounds__(256) void bhist(const int* __restrict__ dstD, const int* __restrict__ dstM,
                                             int* __restrict__ gbh, int E, int Et, int nbD, int nbT)
{
    __shared__ int lh[NBMAX];
    for (int i = threadIdx.x; i < nbT; i += 256) lh[i] = 0;
    __syncthreads();
    for (int j = blockIdx.x * 256 + threadIdx.x; j < Et; j += 256 * gridDim.x) {
        int b = (j < E) ? (dstD[j] >> 6) : (nbD + (dstM[j - E] >> 6));
        atomicAdd(&lh[b], 1);
    }
    __syncthreads();
    for (int b = threadIdx.x; b < nbT; b += 256) {
        int v = lh[b];
        if (v) atomicAdd(&gbh[b], v);
    }
}

// single-block exclusive scan (nb <= 4096, 16 per thread)
__global__ __launch_bounds__(256) void bscan(const int* __restrict__ gbh, int* __restrict__ goff,
                                             int* __restrict__ gcur, int nb)
{
    __shared__ int sp[256];
    int t = threadIdx.x;
    int base = t * 16;
    int a[16];
    int s = 0;
    #pragma unroll
    for (int u = 0; u < 16; ++u) {
        a[u] = (base + u < nb) ? gbh[base + u] : 0;
        s += a[u];
    }
    sp[t] = s;
    __syncthreads();
    for (int o = 1; o < 256; o <<= 1) {
        int y = (t >= o) ? sp[t - o] : 0;
        __syncthreads();
        sp[t] += y;
        __syncthreads();
    }
    int e = sp[t] - s;
    #pragma unroll
    for (int u = 0; u < 16; ++u) {
        if (base + u < nb) { goff[base + u] = e; gcur[base + u] = e; }
        e += a[u];
    }
}

// direct rank-scatter over the combined edge list; edges cached in registers between passes
__global__ __launch_bounds__(256) void bfill(const int* __restrict__ srcD, const int* __restrict__ dstD,
                                             const int* __restrict__ srcM, const int* __restrict__ dstM,
                                             int* __restrict__ gcur, int* __restrict__ ebuf,
                                             int E, int Et, int nbD, int nbT)
{
    __shared__ int lh[NBMAX];
    __shared__ int lst[NBMAX];
    const int t = threadIdx.x;
    const int base = blockIdx.x * BTILE;

    for (int i = t; i < nbT; i += 256) lh[i] = 0;
    __syncthreads();

    int bb[8], pk[8];
    #pragma unroll
    for (int u = 0; u < 8; ++u) {
        int j = base + u * 256 + t;
        if (j < Et) {
            int d, sv;
            if (j < E) { d = dstD[j]; sv = srcD[j]; bb[u] = d >> 6; }
            else       { d = dstM[j - E]; sv = srcM[j - E]; bb[u] = nbD + (d >> 6); }
            pk[u] = ((d & 63) << 17) | sv;
            atomicAdd(&lh[bb[u]], 1);
        } else bb[u] = -1;
    }
    __syncthreads();

    for (int b = t; b < nbT; b += 256) {
        int k = lh[b];
        lst[b] = k ? atomicAdd(&gcur[b], k) : 0;
    }
    __syncthreads();

    #pragma unroll
    for (int u = 0; u < 8; ++u) {
        if (bb[u] >= 0) {
            int pos = atomicAdd(&lst[bb[u]], 1);
            ebuf[pos] = pk[u];
        }
    }
}

// block per bucket: counting sort by src-chunk (src>>10) -> ee (coarse src-ordered), plus dis
__global__ __launch_bounds__(256) void local_sort(const int* __restrict__ ebuf, const int* __restrict__ goff,
                                                  const int* __restrict__ gbh, int* __restrict__ ee,
                                                  float* __restrict__ dis, int nbD, int N, int NM)
{
    __shared__ int lcnt[128];
    __shared__ int lrs[128];
    __shared__ int lcur[128];
    __shared__ int lcd[64];
    const int b = blockIdx.x;
    const int t = threadIdx.x;
    const int off = goff[b];
    const int k = gbh[b];
    const bool isData = b < nbD;

    if (t < 128) lcnt[t] = 0;
    if (t < 64) lcd[t] = 0;
    __syncthreads();
    for (int i = t; i < k; i += 256) {
        int v = ebuf[off + i];
        atomicAdd(&lcnt[(v & 0x1FFFF) >> 10], 1);
        atomicAdd(&lcd[v >> 17], 1);
    }
    __syncthreads();
    if (t < 128) lrs[t] = lcnt[t];
    __syncthreads();
    for (int o = 1; o < 128; o <<= 1) {
        int y = (t < 128 && t >= o) ? lrs[t - o] : 0;
        __syncthreads();
        if (t < 128) lrs[t] += y;
        __syncthreads();
    }
    if (t < 128) lcur[t] = lrs[t] - lcnt[t];
    __syncthreads();
    for (int i = t; i < k; i += 256) {
        int v = ebuf[off + i];
        int pos = atomicAdd(&lcur[(v & 0x1FFFF) >> 10], 1);
        ee[off + pos] = v;
    }
    if (t < 64) {
        int local = (isData ? b : b - nbD) * 64 + t;
        int lim = isData ? N : NM;
        if (local < lim) {
            int dt = lcd[t] + (isData ? 1 : 0);
            dis[(isData ? 0 : N) + local] = dt > 0 ? rsqrtf((float)dt) : 0.0f;
        }
    }
}

// ---- block-per-bucket edge-parallel gather: 32 edge slots x 8 feature lanes, LDS f32 accumulate ----
// h pre-scaled by dis[src]; out = lrelu(dd*(acc (+h[d] if SELF)) + bias)
template <bool SELF, bool FINAL>
__global__ __launch_bounds__(256) void gather_b(const unsigned short* __restrict__ h,
                                                const int* __restrict__ ee,
                                                const int* __restrict__ goff, const int* __restrict__ gbh,
                                                const float* __restrict__ dis, const float* __restrict__ bias,
                                                unsigned short* __restrict__ out,
                                                const float* __restrict__ Wc, const float* __restrict__ bc,
                                                float* __restrict__ fout, int nlim)
{
    __shared__ float acc[64 * 68];   // stride 68: bank spread for ds_add
    const int t = threadIdx.x;
    const int b = blockIdx.x;
    const int off = goff[b];
    const int k = gbh[b];
    for (int i = t; i < 64 * 68; i += 256) acc[i] = 0.f;
    __syncthreads();

    const int slot = t >> 3;   // 0..31
    const int fh = t & 7;      // feature octet
    const char* hb = (const char*)h;

    int i = slot;
    for (; i + 32 < k; i += 64) {
        int v0 = ee[off + i];
        int v1 = ee[off + i + 32];
        uint4 w0 = *(const uint4*)(hb + ((unsigned)(v0 & 0x1FFFF) * 128u + (unsigned)fh * 16u));
        uint4 w1 = *(const uint4*)(hb + ((unsigned)(v1 & 0x1FFFF) * 128u + (unsigned)fh * 16u));
        float* a0 = &acc[(v0 >> 17) * 68 + fh * 8];
        atomicAdd(a0 + 0, asf(w0.x << 16)); atomicAdd(a0 + 1, asf(w0.x & 0xFFFF0000u));
        atomicAdd(a0 + 2, asf(w0.y << 16)); atomicAdd(a0 + 3, asf(w0.y & 0xFFFF0000u));
        atomicAdd(a0 + 4, asf(w0.z << 16)); atomicAdd(a0 + 5, asf(w0.z & 0xFFFF0000u));
        atomicAdd(a0 + 6, asf(w0.w << 16)); atomicAdd(a0 + 7, asf(w0.w & 0xFFFF0000u));
        float* a1 = &acc[(v1 >> 17) * 68 + fh * 8];
        atomicAdd(a1 + 0, asf(w1.x << 16)); atomicAdd(a1 + 1, asf(w1.x & 0xFFFF0000u));
        atomicAdd(a1 + 2, asf(w1.y << 16)); atomicAdd(a1 + 3, asf(w1.y & 0xFFFF0000u));
        atomicAdd(a1 + 4, asf(w1.z << 16)); atomicAdd(a1 + 5, asf(w1.z & 0xFFFF0000u));
        atomicAdd(a1 + 6, asf(w1.w << 16)); atomicAdd(a1 + 7, asf(w1.w & 0xFFFF0000u));
    }
    if (i < k) {
        int v0 = ee[off + i];
        uint4 w0 = *(const uint4*)(hb + ((unsigned)(v0 & 0x1FFFF) * 128u + (unsigned)fh * 16u));
        float* a0 = &acc[(v0 >> 17) * 68 + fh * 8];
        atomicAdd(a0 + 0, asf(w0.x << 16)); atomicAdd(a0 + 1, asf(w0.x & 0xFFFF0000u));
        atomicAdd(a0 + 2, asf(w0.y << 16)); atomicAdd(a0 + 3, asf(w0.y & 0xFFFF0000u));
        atomicAdd(a0 + 4, asf(w0.z << 16)); atomicAdd(a0 + 5, asf(w0.z & 0xFFFF0000u));
        atomicAdd(a0 + 6, asf(w0.w << 16)); atomicAdd(a0 + 7, asf(w0.w & 0xFFFF0000u));
    }
    __syncthreads();

    // epilogue: 4 threads per node, 16 features each
    const int n = t >> 2;
    const int q = t & 3;
    const int node = b * 64 + n;
    if (node >= nlim) return;
    const float dd = dis[node];
    const float* ar = &acc[n * 68 + q * 16];
    float r[16];
    {
        float4 A0 = *(const float4*)(ar + 0);
        float4 A1 = *(const float4*)(ar + 4);
        float4 A2 = *(const float4*)(ar + 8);
        float4 A3 = *(const float4*)(ar + 12);
        r[0] = A0.x; r[1] = A0.y; r[2] = A0.z; r[3] = A0.w;
        r[4] = A1.x; r[5] = A1.y; r[6] = A1.z; r[7] = A1.w;
        r[8] = A2.x; r[9] = A2.y; r[10] = A2.z; r[11] = A2.w;
        r[12] = A3.x; r[13] = A3.y; r[14] = A3.z; r[15] = A3.w;
    }
    if (SELF) {
        const uint4* sp = (const uint4*)(hb + ((unsigned)node * 128u + (unsigned)q * 32u));
        uint4 s0 = sp[0], s1 = sp[1];
        r[0] += asf(s0.x << 16); r[1] += asf(s0.x & 0xFFFF0000u);
        r[2] += asf(s0.y << 16); r[3] += asf(s0.y & 0xFFFF0000u);
        r[4] += asf(s0.z << 16); r[5] += asf(s0.z & 0xFFFF0000u);
        r[6] += asf(s0.w << 16); r[7] += asf(s0.w & 0xFFFF0000u);
        r[8] += asf(s1.x << 16); r[9] += asf(s1.x & 0xFFFF0000u);
        r[10] += asf(s1.y << 16); r[11] += asf(s1.y & 0xFFFF0000u);
        r[12] += asf(s1.z << 16); r[13] += asf(s1.z & 0xFFFF0000u);
        r[14] += asf(s1.w << 16); r[15] += asf(s1.w & 0xFFFF0000u);
    }
    {
        const float* bp = bias + q * 16;
        #pragma unroll
        for (int j = 0; j < 16; ++j) r[j] = lrelu(r[j] * dd + bp[j]);
    }
    if (FINAL) {
        const float* wp = Wc + q * 32;
        float p0 = 0.f, p1 = 0.f;
        #pragma unroll
        for (int j = 0; j < 16; ++j) {
            p0 += r[j] * wp[2 * j + 0];
            p1 += r[j] * wp[2 * j + 1];
        }
        p0 += __shfl_xor(p0, 1); p0 += __shfl_xor(p0, 2);
        p1 += __shfl_xor(p1, 1); p1 += __shfl_xor(p1, 2);
        if (q == 0) {
            float l0 = p0 + bc[0], l1 = p1 + bc[1];
            float m = fmaxf(l0, l1);
            float lse = m + logf(expf(l0 - m) + expf(l1 - m));
            fout[(size_t)node * 2 + 0] = l0 - lse;
            fout[(size_t)node * 2 + 1] = l1 - lse;
        }
    } else {
        uint4 o0, o1;
        o0.x = (unsigned)f2b(r[0]) | ((unsigned)f2b(r[1]) << 16);
        o0.y = (unsigned)f2b(r[2]) | ((unsigned)f2b(r[3]) << 16);
        o0.z = (unsigned)f2b(r[4]) | ((unsigned)f2b(r[5]) << 16);
        o0.w = (unsigned)f2b(r[6]) | ((unsigned)f2b(r[7]) << 16);
        o1.x = (unsigned)f2b(r[8]) | ((unsigned)f2b(r[9]) << 16);
        o1.y = (unsigned)f2b(r[10]) | ((unsigned)f2b(r[11]) << 16);
        o1.z = (unsigned)f2b(r[12]) | ((unsigned)f2b(r[13]) << 16);
        o1.w = (unsigned)f2b(r[14]) | ((unsigned)f2b(r[15]) << 16);
        uint4* op = (uint4*)((char*)out + ((unsigned)node * 128u + (unsigned)q * 32u));
        op[0] = o0; op[1] = o1;
    }
}

extern "C" void kernel_launch(void* const* d_in, const int* in_sizes, int n_in,
                              void* d_out, int out_size, void* d_ws, size_t ws_size,
                              hipStream_t stream)
{
    const float* x      = (const float*)d_in[0];
    const int*   ei     = (const int*)d_in[1];
    const float* mx     = (const float*)d_in[2];
    const int*   mei    = (const int*)d_in[3];
    const float* W_lin  = (const float*)d_in[4];
    const float* b_lin  = (const float*)d_in[5];
    const float* W_mlin = (const float*)d_in[6];
    const float* b_mlin = (const float*)d_in[7];
    const float* W0     = (const float*)d_in[8];
    const float* b0     = (const float*)d_in[9];
    const float* W1     = (const float*)d_in[10];
    const float* b1     = (const float*)d_in[11];
    const float* Wm     = (const float*)d_in[12];
    const float* bm     = (const float*)d_in[13];
    const float* Wc     = (const float*)d_in[14];
    const float* bc     = (const float*)d_in[15];

    const int F  = 128;
    const int N  = in_sizes[0] / F;
    const int E  = in_sizes[1] / 2;
    const int M  = in_sizes[2] / F;
    const int Em = in_sizes[3] / 2;
    const int NM = N + M;
    const int Et = E + Em;
    const int* src  = ei;
    const int* dstp = ei + E;
    const int* msrc = mei;
    const int* mdst = mei + Em;

    unsigned short* hb0 = (unsigned short*)d_ws;        // [NM, H] bf16
    unsigned short* hb1 = hb0 + (size_t)NM * H;         // [NM, H] bf16
    float* disV = (float*)(hb1 + (size_t)NM * H);       // [N + NM]
    int*   ebuf = (int*)(disV + (N + NM));              // [Et]
    int*   ee   = ebuf + Et;                            // [Et] src-chunk-sorted packed
    int*   gbh  = ee + Et;                              // [NBMAX]
    int*   goff = gbh + NBMAX;                          // [NBMAX]
    int*   gcur = goff + NBMAX;                         // [NBMAX]

    const int nbD = (N + 63) / 64;
    const int nbM = (NM + 63) / 64;
    const int nbT = nbD + nbM;

    // input projections (meta rows go straight to concat slot)
    mfma_gemm<128, true, true, true, false><<<(N + 63) / 64, 256, 0, stream>>>(x, W_lin, b_lin, nullptr, hb0, N);
    mfma_gemm<128, true, true, true, false><<<(M + 63) / 64, 256, 0, stream>>>(mx, W_mlin, b_mlin, nullptr, hb0 + (size_t)N * H, M);

    // combined CSR build (data + meta graphs in one pass)
    zero_i<<<(NBMAX + 255) / 256, 256, 0, stream>>>(gbh, NBMAX);
    bhist<<<512, 256, 0, stream>>>(dstp, mdst, gbh, E, Et, nbD, nbT);
    bscan<<<1, 256, 0, stream>>>(gbh, goff, gcur, nbT);
    bfill<<<(Et + BTILE - 1) / BTILE, 256, 0, stream>>>(src, dstp, msrc, mdst, gcur, ebuf, E, Et, nbD, nbT);
    local_sort<<<nbT, 256, 0, stream>>>(ebuf, goff, gbh, ee, disV, nbD, N, NM);

    // GCN layer 0 (GEMM output pre-scaled by dis)
    mfma_gemm<64, false, false, false, true><<<(N + 63) / 64, 256, 0, stream>>>(hb0, W0, nullptr, disV, hb1, N);
    gather_b<true, false><<<nbD, 256, 0, stream>>>(hb1, ee, goff, gbh, disV, b0, hb0, nullptr, nullptr, nullptr, N);

    // GCN layer 1
    mfma_gemm<64, false, false, false, true><<<(N + 63) / 64, 256, 0, stream>>>(hb0, W1, nullptr, disV, hb1, N);
    gather_b<true, false><<<nbD, 256, 0, stream>>>(hb1, ee, goff, gbh, disV, b1, hb0, nullptr, nullptr, nullptr, N);

    // meta fusion GEMM over z = hb0[0..NM), pre-scaled by meta dis
    mfma_gemm<64, false, false, false, true><<<(NM + 63) / 64, 256, 0, stream>>>(hb0, Wm, nullptr, disV + N, hb1, NM);

    // final gather + fused classifier + log_softmax (meta buckets start at nbD)
    gather_b<false, true><<<nbM, 256, 0, stream>>>(hb1, ee, goff + nbD, gbh + nbD, disV + N, bm, nullptr, Wc, bc, (float*)d_out, NM);
}

// Round 10
// 276.021 us; speedup vs baseline: 6.9268x; 6.9268x over previous
//
#include <hip/hip_runtime.h>
#include <cstddef>

static constexpr float ALPHA = 0.2f;
static constexpr int H = 64;
static constexpr int NBMAX = 2048;   // combined buckets (128 nodes each)
static constexpr int BTILE = 2048;   // bfill edges per block (8/thread)

typedef __attribute__((ext_vector_type(8))) short short8;
typedef __attribute__((ext_vector_type(4))) float floatx4;

__device__ __forceinline__ float lrelu(float v) { return v >= 0.0f ? v : ALPHA * v; }

__device__ __forceinline__ float b2f(unsigned short u)
{
    union { unsigned int i; float f; } x;
    x.i = ((unsigned int)u) << 16;
    return x.f;
}

__device__ __forceinline__ unsigned short f2b(float f)
{
    union { float f; unsigned int i; } x;
    x.f = f;
    unsigned int r = x.i + 0x7fffu + ((x.i >> 16) & 1u);  // RNE
    return (unsigned short)(r >> 16);
}

// ---- MFMA GEMM: out[rows,64](bf16) = act(in[rows,K] @ W[K,64] (+bias)) (* scl[row]) ----
// CLS: additionally, for rows < clsN, emit log_softmax(lrelu(acc + clsBias) @ Wc + bc) to fout.
template <int K, bool AF32, bool BIAS, bool ACT, bool SCALE, bool CLS>
__global__ __launch_bounds__(256) void mfma_gemm(
    const void* __restrict__ in_v, const float* __restrict__ W,
    const float* __restrict__ bias, const float* __restrict__ scl,
    unsigned short* __restrict__ out, int rows,
    const float* __restrict__ clsBias, const float* __restrict__ Wc,
    const float* __restrict__ bc, float* __restrict__ fout, int clsN)
{
    constexpr int S = K / 32;
    __shared__ short8 WL[4 * S * 64];

    for (int f = threadIdx.x; f < 4 * S * 64; f += 256) {
        int c = f / (S * 64);
        int rem = f % (S * 64);
        int s = rem / 64;
        int l = rem % 64;
        short8 frag;
        #pragma unroll
        for (int j = 0; j < 8; ++j) {
            int k = s * 32 + (l >> 4) * 8 + j;
            int col = c * 16 + (l & 15);
            frag[j] = (short)f2b(W[k * H + col]);
        }
        WL[f] = frag;
    }
    __syncthreads();

    const int l = threadIdx.x & 63;
    const int wv = threadIdx.x >> 6;
    const int rowBase = blockIdx.x * 64 + wv * 16;
    if (rowBase >= rows) return;
    const int arow = min(rowBase + (l & 15), rows - 1);

    floatx4 acc0 = {0.f, 0.f, 0.f, 0.f};
    floatx4 acc1 = {0.f, 0.f, 0.f, 0.f};
    floatx4 acc2 = {0.f, 0.f, 0.f, 0.f};
    floatx4 acc3 = {0.f, 0.f, 0.f, 0.f};

    #pragma unroll
    for (int s = 0; s < S; ++s) {
        short8 a;
        if (AF32) {
            const float* ap = (const float*)in_v + (size_t)arow * K + s * 32 + (l >> 4) * 8;
            float4 f0 = *(const float4*)(ap + 0);
            float4 f1 = *(const float4*)(ap + 4);
            a[0] = (short)f2b(f0.x); a[1] = (short)f2b(f0.y);
            a[2] = (short)f2b(f0.z); a[3] = (short)f2b(f0.w);
            a[4] = (short)f2b(f1.x); a[5] = (short)f2b(f1.y);
            a[6] = (short)f2b(f1.z); a[7] = (short)f2b(f1.w);
        } else {
            a = *(const short8*)((const unsigned short*)in_v + (size_t)arow * K + s * 32 + (l >> 4) * 8);
        }
        acc0 = __builtin_amdgcn_mfma_f32_16x16x32_bf16(a, WL[(0 * S + s) * 64 + l], acc0, 0, 0, 0);
        acc1 = __builtin_amdgcn_mfma_f32_16x16x32_bf16(a, WL[(1 * S + s) * 64 + l], acc1, 0, 0, 0);
        acc2 = __builtin_amdgcn_mfma_f32_16x16x32_bf16(a, WL[(2 * S + s) * 64 + l], acc2, 0, 0, 0);
        acc3 = __builtin_amdgcn_mfma_f32_16x16x32_bf16(a, WL[(3 * S + s) * 64 + l], acc3, 0, 0, 0);
    }

    #pragma unroll
    for (int j = 0; j < 4; ++j) {
        int row = rowBase + (l >> 4) * 4 + j;
        if (row >= rows) continue;
        unsigned short* orow = out + (size_t)row * H;
        float sc = SCALE ? scl[row] : 1.0f;
        float v;
        int col = l & 15;
        v = acc0[j] + (BIAS ? bias[col] : 0.f);      if (ACT) v = lrelu(v); orow[col]      = f2b(v * sc);
        v = acc1[j] + (BIAS ? bias[col + 16] : 0.f); if (ACT) v = lrelu(v); orow[col + 16] = f2b(v * sc);
        v = acc2[j] + (BIAS ? bias[col + 32] : 0.f); if (ACT) v = lrelu(v); orow[col + 32] = f2b(v * sc);
        v = acc3[j] + (BIAS ? bias[col + 48] : 0.f); if (ACT) v = lrelu(v); orow[col + 48] = f2b(v * sc);

        if (CLS) {
            // data rows in the meta graph have only their self loop (deg=1, dis=1):
            // out = log_softmax(lrelu(acc + clsBias) @ Wc + bc). All 16 lanes of this
            // row group take the same branch, so the shuffle reduce is safe.
            if (row < clsN) {
                float r0 = lrelu(acc0[j] + clsBias[col]);
                float r1 = lrelu(acc1[j] + clsBias[col + 16]);
                float r2 = lrelu(acc2[j] + clsBias[col + 32]);
                float r3 = lrelu(acc3[j] + clsBias[col + 48]);
                float p0 = r0 * Wc[col * 2]            + r1 * Wc[(col + 16) * 2]
                         + r2 * Wc[(col + 32) * 2]     + r3 * Wc[(col + 48) * 2];
                float p1 = r0 * Wc[col * 2 + 1]        + r1 * Wc[(col + 16) * 2 + 1]
                         + r2 * Wc[(col + 32) * 2 + 1] + r3 * Wc[(col + 48) * 2 + 1];
                #pragma unroll
                for (int o = 8; o; o >>= 1) {
                    p0 += __shfl_xor(p0, o);
                    p1 += __shfl_xor(p1, o);
                }
                if (col == 0) {
                    float l0 = p0 + bc[0], l1 = p1 + bc[1];
                    float m = fmaxf(l0, l1);
                    float lse = m + logf(expf(l0 - m) + expf(l1 - m));
                    fout[(size_t)row * 2 + 0] = l0 - lse;
                    fout[(size_t)row * 2 + 1] = l1 - lse;
                }
            }
        }
    }
}

// ---------------- combined bucket-sort CSR build (data graph + meta graph in one pass) ----------------
// virtual bucket space: [0, nbD) data buckets (dst>>7), [nbD, nbD+nbM) meta buckets.
// packed entry = (dstLocal<<17) | src   (src < 2^17, dstLocal < 128)

__global__ __launch_bounds__(256) void zero_i(int* __restrict__ p, int n)
{
    int i = blockIdx.x * 256 + threadIdx.x;
    if (i < n) p[i] = 0;
}

__global__ __launch_bounds__(256) void bhist(const int* __restrict__ dstD, const int* __restrict__ dstM,
                                             int* __restrict__ gbh, int E, int Et, int nbD, int nbT)
{
    __shared__ int lh[NBMAX];
    for (int i = threadIdx.x; i < nbT; i += 256) lh[i] = 0;
    __syncthreads();
    for (int j = blockIdx.x * 256 + threadIdx.x; j < Et; j += 256 * gridDim.x) {
        int b = (j < E) ? (dstD[j] >> 7) : (nbD + (dstM[j - E] >> 7));
        atomicAdd(&lh[b], 1);
    }
    __syncthreads();
    for (int b = threadIdx.x; b < nbT; b += 256) {
        int v = lh[b];
        if (v) atomicAdd(&gbh[b], v);
    }
}

// single-block exclusive scan (nb <= 2048, 8 per thread)
__global__ __launch_bounds__(256) void bscan(const int* __restrict__ gbh, int* __restrict__ goff,
                                             int* __restrict__ gcur, int nb)
{
    __shared__ int sp[256];
    int t = threadIdx.x;
    int base = t * 8;
    int a[8];
    int s = 0;
    #pragma unroll
    for (int u = 0; u < 8; ++u) {
        a[u] = (base + u < nb) ? gbh[base + u] : 0;
        s += a[u];
    }
    sp[t] = s;
    __syncthreads();
    for (int o = 1; o < 256; o <<= 1) {
        int y = (t >= o) ? sp[t - o] : 0;
        __syncthreads();
        sp[t] += y;
        __syncthreads();
    }
    int e = sp[t] - s;
    #pragma unroll
    for (int u = 0; u < 8; ++u) {
        if (base + u < nb) { goff[base + u] = e; gcur[base + u] = e; }
        e += a[u];
    }
}

// direct rank-scatter over the combined edge list; edges cached in registers between passes
__global__ __launch_bounds__(256) void bfill(const int* __restrict__ srcD, const int* __restrict__ dstD,
                                             const int* __restrict__ srcM, const int* __restrict__ dstM,
                                             int* __restrict__ gcur, int* __restrict__ ebuf,
                                             int E, int Et, int nbD, int nbT)
{
    __shared__ int lh[NBMAX];
    __shared__ int lst[NBMAX];
    const int t = threadIdx.x;
    const int base = blockIdx.x * BTILE;

    for (int i = t; i < nbT; i += 256) lh[i] = 0;
    __syncthreads();

    int bb[8], pk[8];
    #pragma unroll
    for (int u = 0; u < 8; ++u) {
        int j = base + u * 256 + t;
        if (j < Et) {
            int d, sv;
            if (j < E) { d = dstD[j]; sv = srcD[j]; bb[u] = d >> 7; }
            else       { d = dstM[j - E]; sv = srcM[j - E]; bb[u] = nbD + (d >> 7); }
            pk[u] = ((d & 127) << 17) | sv;
            atomicAdd(&lh[bb[u]], 1);
        } else bb[u] = -1;
    }
    __syncthreads();

    for (int b = t; b < nbT; b += 256) {
        int k = lh[b];
        lst[b] = k ? atomicAdd(&gcur[b], k) : 0;
    }
    __syncthreads();

    #pragma unroll
    for (int u = 0; u < 8; ++u) {
        if (bb[u] >= 0) {
            int pos = atomicAdd(&lst[bb[u]], 1);
            ebuf[pos] = pk[u];
        }
    }
}

// block per bucket: local counting sort -> esrc (dense) + rs/cnt/dis in virtual node space
__global__ __launch_bounds__(256) void local_csr(const int* __restrict__ ebuf, const int* __restrict__ goff,
                                                 const int* __restrict__ gbh, int* __restrict__ esrc,
                                                 int* __restrict__ rs, int* __restrict__ cnt,
                                                 float* __restrict__ dis, int nbD, int N, int NM)
{
    __shared__ int lcnt[128];
    __shared__ int lrs[128];
    __shared__ int lcur[128];
    const int b = blockIdx.x;
    const int t = threadIdx.x;
    const int off = goff[b];
    const int k = gbh[b];
    const bool isData = b < nbD;

    if (t < 128) lcnt[t] = 0;
    __syncthreads();
    for (int i = t; i < k; i += 256) atomicAdd(&lcnt[ebuf[off + i] >> 17], 1);
    __syncthreads();
    if (t < 128) lrs[t] = lcnt[t];
    __syncthreads();
    for (int o = 1; o < 128; o <<= 1) {
        int y = (t < 128 && t >= o) ? lrs[t - o] : 0;
        __syncthreads();
        if (t < 128) lrs[t] += y;
        __syncthreads();
    }
    if (t < 128) lcur[t] = lrs[t] - lcnt[t];
    __syncthreads();
    for (int i = t; i < k; i += 256) {
        int v = ebuf[off + i];
        int dL = v >> 17;
        int pos = atomicAdd(&lcur[dL], 1);
        esrc[off + pos] = v & 0x1FFFF;
    }
    if (t < 128) {
        int local = isData ? b * 128 + t : (b - nbD) * 128 + t;
        int lim = isData ? N : NM;
        if (local < lim) {
            int slot = isData ? local : N + local;
            int c = lcnt[t];
            rs[slot] = off + (lrs[t] - c);
            cnt[slot] = c;
            int dt = c + (isData ? 1 : 0);
            dis[slot] = dt > 0 ? rsqrtf((float)dt) : 0.0f;
        }
    }
}

// ---- 16-lanes-per-dst gather (R5 structure, pre-scaled h): 16 dst rows per block ----
// h pre-scaled by dis[src]; out = lrelu(dd*(sum hs[s] (+hs[d] if SELF)) + bias)
template <bool SELF, bool FINAL>
__global__ __launch_bounds__(256) void gather16(const unsigned short* __restrict__ h,
                                                const int* __restrict__ esrc,
                                                const int* __restrict__ rs, const int* __restrict__ cnt,
                                                const float* __restrict__ dis, const float* __restrict__ bias,
                                                unsigned short* __restrict__ out,
                                                const float* __restrict__ Wc, const float* __restrict__ bc,
                                                float* __restrict__ fout, int base, int n)
{
    int d = base + blockIdx.x * 16 + (threadIdx.x >> 4);
    if (d >= n) return;
    const int l = threadIdx.x & 15;
    const int beg = rs[d];
    const int c = cnt[d];
    const float dd = dis[d];

    float ax0 = 0.f, ay0 = 0.f, az0 = 0.f, aw0 = 0.f;
    float ax1 = 0.f, ay1 = 0.f, az1 = 0.f, aw1 = 0.f;
    int i = 0;
    for (; i + 2 <= c; i += 2) {
        int s0 = esrc[beg + i], s1 = esrc[beg + i + 1];
        ushort4 v0 = *(const ushort4*)(h + (size_t)s0 * H + l * 4);
        ushort4 v1 = *(const ushort4*)(h + (size_t)s1 * H + l * 4);
        ax0 += b2f(v0.x); ay0 += b2f(v0.y); az0 += b2f(v0.z); aw0 += b2f(v0.w);
        ax1 += b2f(v1.x); ay1 += b2f(v1.y); az1 += b2f(v1.z); aw1 += b2f(v1.w);
    }
    if (i < c) {
        int s = esrc[beg + i];
        ushort4 v = *(const ushort4*)(h + (size_t)s * H + l * 4);
        ax0 += b2f(v.x); ay0 += b2f(v.y); az0 += b2f(v.z); aw0 += b2f(v.w);
    }
    if (SELF) {
        ushort4 v = *(const ushort4*)(h + (size_t)d * H + l * 4);
        ax0 += b2f(v.x); ay0 += b2f(v.y); az0 += b2f(v.z); aw0 += b2f(v.w);
    }

    float rx = (ax0 + ax1) * dd, ry = (ay0 + ay1) * dd, rz = (az0 + az1) * dd, rw = (aw0 + aw1) * dd;
    float4 bb = *(const float4*)(bias + l * 4);
    rx = lrelu(rx + bb.x); ry = lrelu(ry + bb.y); rz = lrelu(rz + bb.z); rw = lrelu(rw + bb.w);

    if (FINAL) {
        int f = l * 4;
        float p0 = rx * Wc[(f + 0) * 2] + ry * Wc[(f + 1) * 2] + rz * Wc[(f + 2) * 2] + rw * Wc[(f + 3) * 2];
        float p1 = rx * Wc[(f + 0) * 2 + 1] + ry * Wc[(f + 1) * 2 + 1] + rz * Wc[(f + 2) * 2 + 1] + rw * Wc[(f + 3) * 2 + 1];
        #pragma unroll
        for (int o = 8; o; o >>= 1) {
            p0 += __shfl_xor(p0, o);
            p1 += __shfl_xor(p1, o);
        }
        if (l == 0) {
            float l0 = p0 + bc[0], l1 = p1 + bc[1];
            float m = fmaxf(l0, l1);
            float lse = m + logf(expf(l0 - m) + expf(l1 - m));
            fout[(size_t)d * 2 + 0] = l0 - lse;
            fout[(size_t)d * 2 + 1] = l1 - lse;
        }
    } else {
        ushort4 o;
        o.x = f2b(rx); o.y = f2b(ry); o.z = f2b(rz); o.w = f2b(rw);
        *(ushort4*)(out + (size_t)d * H + l * 4) = o;
    }
}

extern "C" void kernel_launch(void* const* d_in, const int* in_sizes, int n_in,
                              void* d_out, int out_size, void* d_ws, size_t ws_size,
                              hipStream_t stream)
{
    const float* x      = (const float*)d_in[0];
    const int*   ei     = (const int*)d_in[1];
    const float* mx     = (const float*)d_in[2];
    const int*   mei    = (const int*)d_in[3];
    const float* W_lin  = (const float*)d_in[4];
    const float* b_lin  = (const float*)d_in[5];
    const float* W_mlin = (const float*)d_in[6];
    const float* b_mlin = (const float*)d_in[7];
    const float* W0     = (const float*)d_in[8];
    const float* b0     = (const float*)d_in[9];
    const float* W1     = (const float*)d_in[10];
    const float* b1     = (const float*)d_in[11];
    const float* Wm     = (const float*)d_in[12];
    const float* bm     = (const float*)d_in[13];
    const float* Wc     = (const float*)d_in[14];
    const float* bc     = (const float*)d_in[15];

    const int F  = 128;
    const int N  = in_sizes[0] / F;
    const int E  = in_sizes[1] / 2;
    const int M  = in_sizes[2] / F;
    const int Em = in_sizes[3] / 2;
    const int NM = N + M;
    const int Et = E + Em;
    const int* src  = ei;
    const int* dstp = ei + E;
    const int* msrc = mei;
    const int* mdst = mei + Em;

    unsigned short* hb0 = (unsigned short*)d_ws;        // [NM, H] bf16
    unsigned short* hb1 = hb0 + (size_t)NM * H;         // [NM, H] bf16
    float* disV = (float*)(hb1 + (size_t)NM * H);       // [N + NM]
    int*   cntV = (int*)(disV + (N + NM));              // [N + NM]
    int*   rsV  = cntV + (N + NM);                      // [N + NM]
    int*   esrcA = rsV + (N + NM);                      // [Et]
    int*   ebuf  = esrcA + Et;                          // [Et]
    int*   gbh  = ebuf + Et;                            // [NBMAX]
    int*   goff = gbh + NBMAX;                          // [NBMAX]
    int*   gcur = goff + NBMAX;                         // [NBMAX]

    const int nbD = (N + 127) / 128;
    const int nbM = (NM + 127) / 128;
    const int nbT = nbD + nbM;

    // input projections (meta rows go straight to concat slot)
    mfma_gemm<128, true, true, true, false, false><<<(N + 63) / 64, 256, 0, stream>>>(
        x, W_lin, b_lin, nullptr, hb0, N, nullptr, nullptr, nullptr, nullptr, 0);
    mfma_gemm<128, true, true, true, false, false><<<(M + 63) / 64, 256, 0, stream>>>(
        mx, W_mlin, b_mlin, nullptr, hb0 + (size_t)N * H, M, nullptr, nullptr, nullptr, nullptr, 0);

    // combined CSR build (data + meta graphs in one pass)
    zero_i<<<(NBMAX + 255) / 256, 256, 0, stream>>>(gbh, NBMAX);
    bhist<<<256, 256, 0, stream>>>(dstp, mdst, gbh, E, Et, nbD, nbT);
    bscan<<<1, 256, 0, stream>>>(gbh, goff, gcur, nbT);
    bfill<<<(Et + BTILE - 1) / BTILE, 256, 0, stream>>>(src, dstp, msrc, mdst, gcur, ebuf, E, Et, nbD, nbT);
    local_csr<<<nbT, 256, 0, stream>>>(ebuf, goff, gbh, esrcA, rsV, cntV, disV, nbD, N, NM);

    // GCN layer 0 (GEMM output pre-scaled by dis)
    mfma_gemm<64, false, false, false, true, false><<<(N + 63) / 64, 256, 0, stream>>>(
        hb0, W0, nullptr, disV, hb1, N, nullptr, nullptr, nullptr, nullptr, 0);
    gather16<true, false><<<(N + 15) / 16, 256, 0, stream>>>(
        hb1, esrcA, rsV, cntV, disV, b0, hb0, nullptr, nullptr, nullptr, 0, N);

    // GCN layer 1
    mfma_gemm<64, false, false, false, true, false><<<(N + 63) / 64, 256, 0, stream>>>(
        hb0, W1, nullptr, disV, hb1, N, nullptr, nullptr, nullptr, nullptr, 0);
    gather16<true, false><<<(N + 15) / 16, 256, 0, stream>>>(
        hb1, esrcA, rsV, cntV, disV, b1, hb0, nullptr, nullptr, nullptr, 0, N);

    // meta fusion GEMM over z = hb0[0..NM), pre-scaled by meta dis.
    // Data rows (< N) have deg=1 self-loop in the meta graph (dis=1), so their final
    // output is log_softmax(lrelu(acc + bm) @ Wc + bc) — fused into this epilogue.
    mfma_gemm<64, false, false, false, true, true><<<(NM + 63) / 64, 256, 0, stream>>>(
        hb0, Wm, nullptr, disV + N, hb1, NM, bm, Wc, bc, (float*)d_out, N);

    // final gather + fused classifier + log_softmax over META nodes only (d in [N, NM))
    gather16<false, true><<<(M + 15) / 16, 256, 0, stream>>>(
        hb1, esrcA, rsV + N, cntV + N, disV + N, bm, nullptr, Wc, bc, (float*)d_out, N, NM);
}